// Round 12
// baseline (69.215 us; speedup 1.0000x reference)
//
#include <hip/hip_runtime.h>

#define B_ 16
#define QN 256
#define KN 256
#define DN 256
#define HN 256

#define LOG2E 1.4426950408889634f
#define TWOLOG2E 2.8853900817779268f  // exp2(x*this) = e^{2x}

__device__ inline float readlane_f(float v, int l) {
    return __uint_as_float(__builtin_amdgcn_readlane(__float_as_uint(v), l));
}

// ---------------- Kernel A (fused): projections + exp ----------------
// (unchanged from R11: 16 rows/block, 4r x 4h per thread, W 2-stage pipelined,
//  exp2 applied in epilogue; k-path stored transposed in [h/8][k][8] octets)
__global__ __launch_bounds__(256) void proj_kernel(const float* __restrict__ Xq,
                                                   const float* __restrict__ Xk,
                                                   const float* __restrict__ Wq,
                                                   const float* __restrict__ Wk,
                                                   float* __restrict__ EQ,
                                                   float* __restrict__ EKT,
                                                   float scale) {
    const int nb = (int)gridDim.x >> 1;
    int blk = blockIdx.x;
    const bool is_q = blk < nb;
    const float* X;
    const float* W;
    if (is_q) { X = Xq; W = Wq; }
    else      { X = Xk; W = Wk; blk -= nb; }
    const int row0 = blk * 16;

    __shared__ float xl[16][260];
    __shared__ float trans[16][260];
    const int tid = threadIdx.x;

    {
        const float4* src = (const float4*)(X + (size_t)row0 * DN);
#pragma unroll
        for (int i = 0; i < 4; ++i) {
            int idx = tid + 256 * i;
            int r = idx >> 6, c = (idx & 63) << 2;
            *(float4*)&xl[r][c] = src[idx];
        }
    }
    __syncthreads();

    const int rg = tid >> 6;
    const int h4 = (tid & 63) << 2;

    float4 acc[4];
#pragma unroll
    for (int r = 0; r < 4; ++r) acc[r] = make_float4(0.f, 0.f, 0.f, 0.f);

    float4 wb0[4], wb1[4];
#pragma unroll
    for (int j = 0; j < 4; ++j) wb0[j] = *(const float4*)&W[(size_t)j * HN + h4];

#define PROJ_COMP(WB, D0)                                                      \
    do {                                                                       \
        float4 x[4];                                                           \
        _Pragma("unroll") for (int r = 0; r < 4; ++r)                          \
            x[r] = *(const float4*)&xl[(rg << 2) + r][(D0)];                   \
        _Pragma("unroll") for (int r = 0; r < 4; ++r) {                        \
            acc[r].x = fmaf(x[r].x, WB[0].x, acc[r].x);                        \
            acc[r].y = fmaf(x[r].x, WB[0].y, acc[r].y);                        \
            acc[r].z = fmaf(x[r].x, WB[0].z, acc[r].z);                        \
            acc[r].w = fmaf(x[r].x, WB[0].w, acc[r].w);                        \
            acc[r].x = fmaf(x[r].y, WB[1].x, acc[r].x);                        \
            acc[r].y = fmaf(x[r].y, WB[1].y, acc[r].y);                        \
            acc[r].z = fmaf(x[r].y, WB[1].z, acc[r].z);                        \
            acc[r].w = fmaf(x[r].y, WB[1].w, acc[r].w);                        \
            acc[r].x = fmaf(x[r].z, WB[2].x, acc[r].x);                        \
            acc[r].y = fmaf(x[r].z, WB[2].y, acc[r].y);                        \
            acc[r].z = fmaf(x[r].z, WB[2].z, acc[r].z);                        \
            acc[r].w = fmaf(x[r].z, WB[2].w, acc[r].w);                        \
            acc[r].x = fmaf(x[r].w, WB[3].x, acc[r].x);                        \
            acc[r].y = fmaf(x[r].w, WB[3].y, acc[r].y);                        \
            acc[r].z = fmaf(x[r].w, WB[3].z, acc[r].z);                        \
            acc[r].w = fmaf(x[r].w, WB[3].w, acc[r].w);                        \
        }                                                                      \
    } while (0)

    for (int d0 = 0; d0 < DN; d0 += 8) {
#pragma unroll
        for (int j = 0; j < 4; ++j)
            wb1[j] = *(const float4*)&W[(size_t)(d0 + 4 + j) * HN + h4];
        PROJ_COMP(wb0, d0);
        if (d0 + 8 < DN) {
#pragma unroll
            for (int j = 0; j < 4; ++j)
                wb0[j] = *(const float4*)&W[(size_t)(d0 + 8 + j) * HN + h4];
        }
        PROJ_COMP(wb1, d0 + 4);
    }

#pragma unroll
    for (int r = 0; r < 4; ++r) {
        acc[r].x = __builtin_amdgcn_exp2f(acc[r].x * scale);
        acc[r].y = __builtin_amdgcn_exp2f(acc[r].y * scale);
        acc[r].z = __builtin_amdgcn_exp2f(acc[r].z * scale);
        acc[r].w = __builtin_amdgcn_exp2f(acc[r].w * scale);
    }

    if (is_q) {
#pragma unroll
        for (int r = 0; r < 4; ++r)
            *(float4*)&EQ[(size_t)(row0 + (rg << 2) + r) * HN + h4] = acc[r];
    } else {
#pragma unroll
        for (int r = 0; r < 4; ++r)
            *(float4*)&trans[(rg << 2) + r][h4] = acc[r];
        __syncthreads();
        const int b = row0 >> 8, kloc0 = row0 & 255;
        float* dstb = EKT + (size_t)b * 32 * 256 * 8;
#pragma unroll
        for (int i = 0; i < 4; ++i) {
            int idx = i * 256 + tid;
            int u4 = (idx & 1) << 2;
            int kj = (idx >> 1) & 15;
            int h0 = idx >> 5;
            float4 val = *(const float4*)&trans[kj][h0 * 8 + u4];
            *(float4*)&dstb[((size_t)h0 * 256 + kloc0 + kj) * 8 + u4] = val;
        }
    }
}

// ------------- Kernel B (fused): score + masked softmax + PV ----------------
// Block = 4 waves, covers 8 Q ROWS; wave = one k-group (k = 64w+lane) for all 8 q.
// Per 8-h window: 2 b128 k-loads feed 64 rcp + 128 fma (~512 issue cyc) -> L2
// latency fully hidden at 2 waves/SIMD. Batch-interleaved block mapping
// (b = id&15) mixes lens across the dispatch timeline (no all-long tail).
// q/wv in LDS (b128 broadcasts); k loads 2-deep pipelined; PV 4-deep batched.
__global__ __launch_bounds__(256, 4) void attn_kernel(const float* __restrict__ EQ,
                                                      const float* __restrict__ EKT,
                                                      const float* __restrict__ wv,
                                                      const int* __restrict__ lens,
                                                      const float* __restrict__ V,
                                                      float* __restrict__ OUT) {
    const int b = blockIdx.x & 15;
    const int q0 = (blockIdx.x >> 4) * 8;
    const int len = lens[b];

    __shared__ float eq_lds[8][256];    // 8 KB
    __shared__ float wv_lds[256];       // 1 KB
    __shared__ float part[4][8][256];   // 32 KB
    __shared__ float maxb[4][8];
    __shared__ float sumb[4][8];

    const int tid = threadIdx.x;
    const int w = tid >> 6, lane = tid & 63;

    {
        // stage 8 eq rows (8*256 = 512 float4) + wv
        const float4* src = (const float4*)&EQ[((size_t)b * QN + q0) * HN];
        float4* dst = (float4*)&eq_lds[0][0];
        dst[tid] = src[tid];
        dst[tid + 256] = src[tid + 256];
        if (tid < 64) *(float4*)&wv_lds[tid << 2] = *(const float4*)&wv[tid << 2];
    }
    __syncthreads();

    const bool act = (w * 64) < len;          // wave-uniform
    float acc[8] = {0.f, 0.f, 0.f, 0.f, 0.f, 0.f, 0.f, 0.f};

#define WINDOW(KA, KB, H8)                                                        \
    do {                                                                          \
        float4 wa = *(const float4*)&wv_lds[(H8)];                                \
        float4 wb = *(const float4*)&wv_lds[(H8) + 4];                            \
        _Pragma("unroll") for (int qq = 0; qq < 8; ++qq) {                        \
            float4 qa = *(const float4*)&eq_lds[qq][(H8)];                        \
            float4 qb = *(const float4*)&eq_lds[qq][(H8) + 4];                    \
            float t = acc[qq];                                                    \
            t = fmaf(wa.x, __builtin_amdgcn_rcpf(fmaf(qa.x, KA.x, 1.f)), t);      \
            t = fmaf(wa.y, __builtin_amdgcn_rcpf(fmaf(qa.y, KA.y, 1.f)), t);      \
            t = fmaf(wa.z, __builtin_amdgcn_rcpf(fmaf(qa.z, KA.z, 1.f)), t);      \
            t = fmaf(wa.w, __builtin_amdgcn_rcpf(fmaf(qa.w, KA.w, 1.f)), t);      \
            t = fmaf(wb.x, __builtin_amdgcn_rcpf(fmaf(qb.x, KB.x, 1.f)), t);      \
            t = fmaf(wb.y, __builtin_amdgcn_rcpf(fmaf(qb.y, KB.y, 1.f)), t);      \
            t = fmaf(wb.z, __builtin_amdgcn_rcpf(fmaf(qb.z, KB.z, 1.f)), t);      \
            t = fmaf(wb.w, __builtin_amdgcn_rcpf(fmaf(qb.w, KB.w, 1.f)), t);      \
            acc[qq] = t;                                                          \
        }                                                                         \
    } while (0)

    if (act) {
        const float* kp = EKT + (size_t)b * (32 * 256 * 8) + (size_t)(w * 64 + lane) * 8;
        float4 ka0 = *(const float4*)&kp[0];
        float4 kb0 = *(const float4*)&kp[4];
        float4 ka1, kb1;
        for (int hw = 0; hw < 32; hw += 2) {
            const float* kp1 = kp + (size_t)(hw + 1) * 2048;
            ka1 = *(const float4*)&kp1[0];
            kb1 = *(const float4*)&kp1[4];
            WINDOW(ka0, kb0, hw * 8);
            if (hw + 2 < 32) {
                const float* kp2 = kp + (size_t)(hw + 2) * 2048;
                ka0 = *(const float4*)&kp2[0];
                kb0 = *(const float4*)&kp2[4];
            }
            WINDOW(ka1, kb1, hw * 8 + 8);
        }
    }

    const bool kvalid = (w * 64 + lane) < len;
    float p[8];
#pragma unroll
    for (int qq = 0; qq < 8; ++qq) {
        float x = kvalid ? (-2.f * acc[qq]) : -1e6f;
        acc[qq] = x;
        float mm = x;
#pragma unroll
        for (int off = 32; off; off >>= 1) mm = fmaxf(mm, __shfl_xor(mm, off, 64));
        if (lane == 0) maxb[w][qq] = mm;
    }
    __syncthreads();
#pragma unroll
    for (int qq = 0; qq < 8; ++qq) {
        float g = fmaxf(fmaxf(maxb[0][qq], maxb[1][qq]),
                        fmaxf(maxb[2][qq], maxb[3][qq]));
        float pp = __builtin_amdgcn_exp2f((acc[qq] - g) * LOG2E);
        p[qq] = pp;
        float ss = pp;
#pragma unroll
        for (int off = 32; off; off >>= 1) ss += __shfl_xor(ss, off, 64);
        if (lane == 0) sumb[w][qq] = ss;
    }
    __syncthreads();
#pragma unroll
    for (int qq = 0; qq < 8; ++qq) {
        float t = (sumb[0][qq] + sumb[1][qq]) + (sumb[2][qq] + sumb[3][qq]);
        p[qq] *= 1.f / t;
    }

    // PV: wave w covers its 64 k rows (clamped to len); 4-deep batched V loads
    float4 op[8];
#pragma unroll
    for (int qq = 0; qq < 8; ++qq) op[qq] = make_float4(0.f, 0.f, 0.f, 0.f);
    if (act) {
        int kmax = len - w * 64;
        if (kmax > 64) kmax = 64;
        const float* vb = V + ((size_t)b * KN + (size_t)w * 64) * DN + (lane << 2);

#define PV_STEP(KK, VV)                                                        \
    do {                                                                       \
        _Pragma("unroll") for (int qq = 0; qq < 8; ++qq) {                     \
            float bp = readlane_f(p[qq], (KK));                                \
            op[qq].x = fmaf(bp, VV.x, op[qq].x);                               \
            op[qq].y = fmaf(bp, VV.y, op[qq].y);                               \
            op[qq].z = fmaf(bp, VV.z, op[qq].z);                               \
            op[qq].w = fmaf(bp, VV.w, op[qq].w);                               \
        }                                                                      \
    } while (0)

        int kk = 0;
        for (; kk + 4 <= kmax; kk += 4) {
            float4 v0 = *(const float4*)&vb[(size_t)(kk + 0) * DN];
            float4 v1 = *(const float4*)&vb[(size_t)(kk + 1) * DN];
            float4 v2 = *(const float4*)&vb[(size_t)(kk + 2) * DN];
            float4 v3 = *(const float4*)&vb[(size_t)(kk + 3) * DN];
            PV_STEP(kk + 0, v0);
            PV_STEP(kk + 1, v1);
            PV_STEP(kk + 2, v2);
            PV_STEP(kk + 3, v3);
        }
        for (; kk < kmax; ++kk) {
            float4 v0 = *(const float4*)&vb[(size_t)kk * DN];
            PV_STEP(kk, v0);
        }
    }
    {
        const int d4 = lane << 2;
#pragma unroll
        for (int qq = 0; qq < 8; ++qq) *(float4*)&part[w][qq][d4] = op[qq];
    }
    __syncthreads();

    // cross-wave O reduce: thread (q=tid>>6 and q+4, ln=tid&63)
    {
        const int ln = tid & 63;
        const int d4 = ln << 2;
#pragma unroll
        for (int half = 0; half < 2; ++half) {
            const int q = (tid >> 6) + half * 4;
            float4 r0 = *(const float4*)&part[0][q][d4];
            float4 r1 = *(const float4*)&part[1][q][d4];
            float4 r2 = *(const float4*)&part[2][q][d4];
            float4 r3 = *(const float4*)&part[3][q][d4];
            float4 r = make_float4((r0.x + r1.x) + (r2.x + r3.x),
                                   (r0.y + r1.y) + (r2.y + r3.y),
                                   (r0.z + r1.z) + (r2.z + r3.z),
                                   (r0.w + r1.w) + (r2.w + r3.w));
            *(float4*)&OUT[((size_t)b * QN + q0 + q) * DN + d4] = r;
        }
    }
}

extern "C" void kernel_launch(void* const* d_in, const int* in_sizes, int n_in,
                              void* d_out, int out_size, void* d_ws, size_t ws_size,
                              hipStream_t stream) {
    const float* queries = (const float*)d_in[0];
    const float* keys    = (const float*)d_in[1];
    const float* values  = (const float*)d_in[2];
    const int*   lens    = (const int*)d_in[3];
    const float* Wq      = (const float*)d_in[4];
    const float* Wk      = (const float*)d_in[5];
    const float* wv      = (const float*)d_in[6];
    float* out = (float*)d_out;

    float* eq  = (float*)d_ws;                       // [B,Q,H]   4 MB (exp'd, row-major)
    float* ekT = eq + (size_t)B_ * QN * HN;          // [B,32,K,8] 4 MB (exp'd, octets)

    proj_kernel<<<(B_ * QN + B_ * KN) / 16, 256, 0, stream>>>(
        queries, keys, Wq, Wk, eq, ekT, TWOLOG2E);

    attn_kernel<<<(QN / 8) * B_, 256, 0, stream>>>(eq, ekT, wv, lens, values, out);
}